// Round 10
// baseline (2218.174 us; speedup 1.0000x reference)
//
#include <hip/hip_runtime.h>
#include <math.h>

#define NB     262144   // batch (tokens)
#define DD     512      // d_routing
#define NG     4        // groups
#define NGS    4        // group size
#define NOUT   20       // 4 group logits + 16 in-group logits

#define TPB    256      // 4 waves/block
#define TOKS   256      // tokens per block; each wave owns 64 (8 passes x 8)

typedef float f32x4 __attribute__((ext_vector_type(4)));

// Cooperative-token scheme: lane = 8*t + d. The 8 lanes of a token read one
// full 128B line per pass-iteration (perfectly coalesced, straight to VGPRs,
// consumed once -- no LDS staging of x, no barriers in the main loop).
// Weights live in LDS (staged once): per (o,iter) the wave reads 8 distinct
// consecutive 16B slots spanning all 32 banks, 8-lane broadcast each ->
// conflict-free. Partials reduce across the 8-lane group via __shfl_xor.
__global__ __launch_bounds__(TPB, 4) void router_k(
    const float* __restrict__ x,        // [NB, DD]
    const float* __restrict__ group_w,  // [NG, DD]
    const float* __restrict__ group_b,  // [NG]
    const float* __restrict__ in_w,     // [NG*NGS, DD]
    const float* __restrict__ in_b,     // [NG, NGS]
    const int*   __restrict__ experts,  // [NG, NGS]
    float*       __restrict__ out)      // [2*NB*2]: indices then weights, fp32
{
    __shared__ float wlds[NOUT * DD];   // 40 KB: rows 0..3 group_w, 4..19 in_w
    {
        const float4* gw4 = reinterpret_cast<const float4*>(group_w);
        const float4* iw4 = reinterpret_cast<const float4*>(in_w);
        float4* wl4 = reinterpret_cast<float4*>(wlds);
        for (int i = threadIdx.x; i < (NG * DD) / 4; i += TPB)
            wl4[i] = gw4[i];
        for (int i = threadIdx.x; i < (NG * NGS * DD) / 4; i += TPB)
            wl4[(NG * DD) / 4 + i] = iw4[i];
    }
    __syncthreads();   // the only barrier; weights are read-only afterwards

    const int tid  = threadIdx.x;
    const int wid  = tid >> 6;
    const int lane = tid & 63;
    const int tgrp = lane >> 3;   // token-in-pass (0..7)
    const int d8   = lane & 7;    // dim-chunk owner (0..7)

    // This wave's 64 tokens: blk*256 + wid*64 + p*8 + tgrp, p = 0..7.
    const int wave_tok0 = blockIdx.x * TOKS + wid * 64;

    float2* outi = reinterpret_cast<float2*>(out);
    float2* outw = reinterpret_cast<float2*>(out + (size_t)NB * 2);

#pragma unroll 1
    for (int p = 0; p < 8; ++p) {
        const int tok = wave_tok0 + p * 8 + tgrp;
        const float* xr = x + (size_t)tok * DD + d8 * 4;

        float acc[NOUT];
#pragma unroll
        for (int o = 0; o < NOUT; ++o) acc[o] = 0.f;

        // 16 iterations: this lane covers dims it*32 + d8*4 .. +4.
#pragma unroll
        for (int it = 0; it < 16; ++it) {
            const f32x4 xv = *reinterpret_cast<const f32x4*>(xr + it * 32);
#pragma unroll
            for (int o = 0; o < NOUT; ++o) {
                const f32x4 wv = *reinterpret_cast<const f32x4*>(
                    &wlds[o * DD + it * 32 + d8 * 4]);
                float a = acc[o];
                a = fmaf(xv.x, wv.x, a);
                a = fmaf(xv.y, wv.y, a);
                a = fmaf(xv.z, wv.z, a);
                a = fmaf(xv.w, wv.w, a);
                acc[o] = a;
            }
        }

        // Reduce the 20 partials across the 8-lane group (xor 1,2,4 = DPP).
#pragma unroll
        for (int o = 0; o < NOUT; ++o) {
            float v = acc[o];
            v += __shfl_xor(v, 1);
            v += __shfl_xor(v, 2);
            v += __shfl_xor(v, 4);
            acc[o] = v;   // all 8 lanes now hold the token's logit o
        }

        // ---- epilogue (all 8 lanes redundantly; lane d8==0 writes) ----
        float gl[NG];
#pragma unroll
        for (int g = 0; g < NG; ++g) gl[g] = acc[g] + group_b[g];
        int bg = 0;
        float bv = gl[0];
#pragma unroll
        for (int g = 1; g < NG; ++g)
            if (gl[g] > bv) { bv = gl[g]; bg = g; }

        float il[NGS];
#pragma unroll
        for (int k = 0; k < NGS; ++k) il[k] = 0.f;
#pragma unroll
        for (int g = 0; g < NG; ++g) {
            const bool sel = (g == bg);
#pragma unroll
            for (int k = 0; k < NGS; ++k)
                il[k] = sel ? acc[NG + g * NGS + k] : il[k];
        }
#pragma unroll
        for (int k = 0; k < NGS; ++k) il[k] += in_b[bg * NGS + k];

        float m = fmaxf(fmaxf(il[0], il[1]), fmaxf(il[2], il[3]));
        float pr[NGS];
        float s = 0.f;
#pragma unroll
        for (int k = 0; k < NGS; ++k) { pr[k] = expf(il[k] - m); s += pr[k]; }
        const float inv = 1.0f / s;
#pragma unroll
        for (int k = 0; k < NGS; ++k) pr[k] *= inv;

        int i1 = 0;
        float v1 = pr[0];
#pragma unroll
        for (int k = 1; k < NGS; ++k)
            if (pr[k] > v1) { v1 = pr[k]; i1 = k; }
        int i2 = -1;
        float v2 = -3.0e38f;
#pragma unroll
        for (int k = 0; k < NGS; ++k)
            if (k != i1 && pr[k] > v2) { v2 = pr[k]; i2 = k; }

        if (d8 == 0) {
            const int id1 = experts[bg * NGS + i1];
            const int id2 = experts[bg * NGS + i2];
            outi[tok] = make_float2((float)id1, (float)id2);
            outw[tok] = make_float2(v1, v2);
        }
    }
}

extern "C" void kernel_launch(void* const* d_in, const int* in_sizes, int n_in,
                              void* d_out, int out_size, void* d_ws, size_t ws_size,
                              hipStream_t stream) {
    const float* x  = (const float*)d_in[0];
    const float* gw = (const float*)d_in[1];
    const float* gb = (const float*)d_in[2];
    const float* iw = (const float*)d_in[3];
    const float* ib = (const float*)d_in[4];
    const int*   et = (const int*)d_in[5];
    float* out = (float*)d_out;

    router_k<<<dim3(NB / TOKS), dim3(TPB), 0, stream>>>(x, gw, gb, iw, ib, et, out);
}

// Round 11
// 164.776 us; speedup vs baseline: 13.4617x; 13.4617x over previous
//
#include <hip/hip_runtime.h>
#include <math.h>

#define NB     262144   // batch (tokens)
#define DD     512      // d_routing
#define NG     4        // groups
#define NGS    4        // group size
#define NOUT   20       // 4 group logits + 16 in-group logits

#define TPB    256      // threads per block (4 waves)
#define T      2        // tokens per thread (shares w-broadcasts across 2 tokens)
#define TOKS   512      // tokens per block
#define CH     32       // floats of D per chunk per token (one full 128B line)
#define NCHUNK 16       // DD / CH
#define GRP    260      // 8 tokens * 32 floats + 4 pad floats (bank spread)
#define NXG    64       // staging groups per chunk (TOKS/8)
#define WROWS  24       // 20 weight rows padded to 24 (3 full instructions)

typedef float f32x4 __attribute__((ext_vector_type(4)));

// LDS dest: wave-uniform base + lane*16B, linear, compile-time buffer symbol
// (R6/R8 lesson: runtime-selected dests are catastrophic).
#define GLOAD_LDS16(gsrc, ldst)                                                \
    __builtin_amdgcn_global_load_lds(                                          \
        (const __attribute__((address_space(1))) unsigned int*)(gsrc),         \
        (__attribute__((address_space(3))) unsigned int*)(ldst), 16, 0, 0)

// R5's proven single-buffered schedule, T=2: stage -> sync -> compute -> sync.
// Per chunk, each w-broadcast ds_read feeds FMAs for TWO tokens, halving the
// per-token LDS-pipe cost (R5's suspected residual limiter).
__global__ __launch_bounds__(TPB, 2) void router_k(
    const float* __restrict__ x,        // [NB, DD]
    const float* __restrict__ group_w,  // [NG, DD]
    const float* __restrict__ group_b,  // [NG]
    const float* __restrict__ in_w,     // [NG*NGS, DD]
    const float* __restrict__ in_b,     // [NG, NGS]
    const int*   __restrict__ experts,  // [NG, NGS]
    float*       __restrict__ out)      // [2*NB*2]: indices then weights, fp32
{
    __shared__ float xbuf[NXG * GRP];   // 66560 B
    __shared__ float wbuf[WROWS * CH];  //  3072 B

    const int tid  = threadIdx.x;
    const int wid  = tid >> 6;          // 0..3
    const int lane = tid & 63;
    const int tok0 = blockIdx.x * TOKS;

    const int lrow = lane >> 3;         // token-in-group for staging
    const int lcol = (lane & 7) * 4;    // float offset within 128B line

    // Weight source rows for the 3 staging instructions (clamp-dup pads).
    const float* wrow[3];
#pragma unroll
    for (int m = 0; m < 3; ++m) {
        int R = m * 8 + lrow;
        if (R > 19) R = 19;
        wrow[m] = (R < NG) ? (group_w + (size_t)R * DD)
                           : (in_w + (size_t)(R - NG) * DD);
    }

    // This thread's two token slots inside the buffer: tokens tid and tid+256.
    const int xoff0 = (tid >> 3) * GRP + (tid & 7) * CH;
    const int xoff1 = xoff0 + 32 * GRP;          // +256 tokens = +32 groups

    float acc0[NOUT], acc1[NOUT];
#pragma unroll
    for (int o = 0; o < NOUT; ++o) { acc0[o] = 0.f; acc1[o] = 0.f; }

#pragma unroll 1
    for (int ch = 0; ch < NCHUNK; ++ch) {
        const int dd = ch * CH;

        // ---- stage x chunk: wave wid issues groups k = wid*16 .. +15.
        // Each instr: 8 tokens x one full 128B line -> 1KB linear LDS dest.
#pragma unroll
        for (int kk = 0; kk < 16; ++kk) {
            const int k = wid * 16 + kk;
            const float* src =
                x + (size_t)(tok0 + k * 8 + lrow) * DD + dd + lcol;
            GLOAD_LDS16(src, &xbuf[k * GRP]);
        }

        // ---- stage w chunk (24 rows x 32 floats): wave 0, 3 instructions.
        if (wid == 0) {
#pragma unroll
            for (int m = 0; m < 3; ++m)
                GLOAD_LDS16(wrow[m] + dd + lcol, &wbuf[m * 8 * CH]);
        }

        __syncthreads();   // vmcnt(0) drain + barrier: chunk ready

        // ---- compute: per granule g, 2 x-reads + 20 shared w-broadcasts.
#pragma unroll
        for (int g = 0; g < 8; ++g) {
            const f32x4 xv0 = *(const f32x4*)&xbuf[xoff0 + g * 4];
            const f32x4 xv1 = *(const f32x4*)&xbuf[xoff1 + g * 4];
#pragma unroll
            for (int o = 0; o < NOUT; ++o) {
                const f32x4 w = *(const f32x4*)&wbuf[o * CH + g * 4];
                float a0 = acc0[o];
                float a1 = acc1[o];
                a0 = fmaf(xv0.x, w.x, a0); a1 = fmaf(xv1.x, w.x, a1);
                a0 = fmaf(xv0.y, w.y, a0); a1 = fmaf(xv1.y, w.y, a1);
                a0 = fmaf(xv0.z, w.z, a0); a1 = fmaf(xv1.z, w.z, a1);
                a0 = fmaf(xv0.w, w.w, a0); a1 = fmaf(xv1.w, w.w, a1);
                acc0[o] = a0;
                acc1[o] = a1;
            }
        }

        __syncthreads();   // all reads done before next chunk overwrites
    }

    // ---- epilogue for both tokens (proven R4 dual-token path) ----
    float2* outi = reinterpret_cast<float2*>(out);
    float2* outw = reinterpret_cast<float2*>(out + (size_t)NB * 2);

#pragma unroll
    for (int tk = 0; tk < T; ++tk) {
        const float* acc = (tk == 0) ? acc0 : acc1;   // unroll-constant select
        const int t = tok0 + tid + tk * 256;

        // group argmax (first-max tie-break, matches jnp.argmax)
        float gl[NG];
#pragma unroll
        for (int g = 0; g < NG; ++g) gl[g] = acc[g] + group_b[g];
        int bg = 0;
        float bv = gl[0];
#pragma unroll
        for (int g = 1; g < NG; ++g)
            if (gl[g] > bv) { bv = gl[g]; bg = g; }

        // select chosen group's in-logits without runtime indexing
        float il[NGS];
#pragma unroll
        for (int k = 0; k < NGS; ++k) il[k] = 0.f;
#pragma unroll
        for (int g = 0; g < NG; ++g) {
            const bool sel = (g == bg);
#pragma unroll
            for (int k = 0; k < NGS; ++k)
                il[k] = sel ? acc[NG + g * NGS + k] : il[k];
        }
#pragma unroll
        for (int k = 0; k < NGS; ++k) il[k] += in_b[bg * NGS + k];

        // softmax (fp32, subtract-max)
        float m = fmaxf(fmaxf(il[0], il[1]), fmaxf(il[2], il[3]));
        float p[NGS];
        float s = 0.f;
#pragma unroll
        for (int k = 0; k < NGS; ++k) { p[k] = expf(il[k] - m); s += p[k]; }
        const float inv = 1.0f / s;
#pragma unroll
        for (int k = 0; k < NGS; ++k) p[k] *= inv;

        // top-2 (descending, lower-index-on-tie, matches lax.top_k)
        int i1 = 0;
        float v1 = p[0];
#pragma unroll
        for (int k = 1; k < NGS; ++k)
            if (p[k] > v1) { v1 = p[k]; i1 = k; }
        int i2 = -1;
        float v2 = -3.0e38f;
#pragma unroll
        for (int k = 0; k < NGS; ++k)
            if (k != i1 && p[k] > v2) { v2 = p[k]; i2 = k; }

        const int id1 = experts[bg * NGS + i1];
        const int id2 = experts[bg * NGS + i2];

        outi[t] = make_float2((float)id1, (float)id2);
        outw[t] = make_float2(v1, v2);
    }
}

extern "C" void kernel_launch(void* const* d_in, const int* in_sizes, int n_in,
                              void* d_out, int out_size, void* d_ws, size_t ws_size,
                              hipStream_t stream) {
    const float* x  = (const float*)d_in[0];
    const float* gw = (const float*)d_in[1];
    const float* gb = (const float*)d_in[2];
    const float* iw = (const float*)d_in[3];
    const float* ib = (const float*)d_in[4];
    const int*   et = (const int*)d_in[5];
    float* out = (float*)d_out;

    router_k<<<dim3(NB / TOKS), dim3(TPB), 0, stream>>>(x, gw, gb, iw, ib, et, out);
}